// Round 7
// baseline (28.753 us; speedup 1.0000x reference)
//
#include <hip/hip_runtime.h>
#include <hip/hip_bf16.h>
#include <math.h>

#define TPB 256
#define SLAB 32  // pred points per block; grid = B * (N/SLAB) = 1024 -> 4 blocks/CU

// Single-pass chamfer, occupancy-tuned. Block = (batch b, 32-point pred slab).
// Targets -> registers (8 per thread; 256 threads cover all 2048 targets).
// Pred slab -> LDS as (x,y,z,0.5*p^2).
// Compute: per slab point p (broadcast ds_read_b128), each thread takes the
// min over its 8 targets of s = 0.5*t^2 - p.t (monotone in d^2), writes one
// candidate to L[p][tid] (consecutive-lane writes, conflict-free).
// Reduce: 8 threads per point scan 32 columns each with an octant-rotated
// start (max 2-way bank aliasing = free), 3x shfl_xor merge, then sqrt /
// asym blend; one atomicAdd(out) per block.
__global__ __launch_bounds__(TPB, 4) void chamfer_onepass_kernel(
    const float* __restrict__ pred, const float* __restrict__ targ,
    const float* __restrict__ sym_flag, float* __restrict__ out,
    int N, int B, int slabsPerBatch, float invNB) {
  __shared__ float4 sh[SLAB];       // pred (x,y,z, 0.5p^2)
  __shared__ float asy[SLAB];       // per-point asym distance
  __shared__ float L[SLAB][TPB + 1];  // candidate mins
  __shared__ float cv[SLAB];        // per-leader blended loss

  const int b = blockIdx.x / slabsPerBatch;
  const int slab = blockIdx.x % slabsPerBatch;
  const int t = threadIdx.x;
  const int slabBase = slab * SLAB;

  // ---- this thread's 8 targets into regs (negated) + 0.5*t^2
  float ntx[8], nty[8], ntz[8], ht2[8];
  {
    const float4* tg4 = (const float4*)(targ + ((size_t)b * N + t * 8) * 3);
    float tf[24];
#pragma unroll
    for (int k = 0; k < 6; ++k) {
      const float4 v = tg4[k];
      tf[4 * k] = v.x; tf[4 * k + 1] = v.y;
      tf[4 * k + 2] = v.z; tf[4 * k + 3] = v.w;
    }
#pragma unroll
    for (int j = 0; j < 8; ++j) {
      const float x = tf[3 * j], y = tf[3 * j + 1], z = tf[3 * j + 2];
      ntx[j] = -x; nty[j] = -y; ntz[j] = -z;
      ht2[j] = 0.5f * (x * x + y * y + z * z);
    }
  }

  // ---- stage pred slab + per-point asym term
  if (t < SLAB) {
    const size_t n = (size_t)b * N + slabBase + t;
    const float px = pred[n * 3], py = pred[n * 3 + 1], pz = pred[n * 3 + 2];
    sh[t] = make_float4(px, py, pz, 0.5f * (px * px + py * py + pz * pz));
    const float dx = px - targ[n * 3];
    const float dy = py - targ[n * 3 + 1];
    const float dz = pz - targ[n * 3 + 2];
    asy[t] = sqrtf(dx * dx + dy * dy + dz * dz);
  }
  __syncthreads();

  // ---- compute phase: candidate min over this thread's 8 targets, per point
#pragma unroll 8
  for (int p = 0; p < SLAB; ++p) {
    const float4 t4 = sh[p];  // broadcast read
    const float s0 = fmaf(ntx[0], t4.x, fmaf(nty[0], t4.y, fmaf(ntz[0], t4.z, ht2[0])));
    const float s1 = fmaf(ntx[1], t4.x, fmaf(nty[1], t4.y, fmaf(ntz[1], t4.z, ht2[1])));
    const float s2 = fmaf(ntx[2], t4.x, fmaf(nty[2], t4.y, fmaf(ntz[2], t4.z, ht2[2])));
    const float s3 = fmaf(ntx[3], t4.x, fmaf(nty[3], t4.y, fmaf(ntz[3], t4.z, ht2[3])));
    const float s4 = fmaf(ntx[4], t4.x, fmaf(nty[4], t4.y, fmaf(ntz[4], t4.z, ht2[4])));
    const float s5 = fmaf(ntx[5], t4.x, fmaf(nty[5], t4.y, fmaf(ntz[5], t4.z, ht2[5])));
    const float s6 = fmaf(ntx[6], t4.x, fmaf(nty[6], t4.y, fmaf(ntz[6], t4.z, ht2[6])));
    const float s7 = fmaf(ntx[7], t4.x, fmaf(nty[7], t4.y, fmaf(ntz[7], t4.z, ht2[7])));
    const float m = fminf(fminf(fminf(s0, s1), fminf(s2, s3)),
                          fminf(fminf(s4, s5), fminf(s6, s7)));
    L[p][t] = m;  // consecutive-lane writes: conflict-free
  }
  __syncthreads();

  // ---- reduce phase: 8 threads/point, octant-rotated column scan
  const int prow = t >> 3;  // 0..31: point
  const int oct = t & 7;    // 0..7 : column octant
  {
    float m = 3.4e38f;
#pragma unroll 8
    for (int i = 0; i < 32; ++i) {
      const int cc = (oct << 5) | ((i + (oct << 2)) & 31);  // rotated start
      m = fminf(m, L[prow][cc]);
    }
    m = fminf(m, __shfl_xor(m, 1));
    m = fminf(m, __shfl_xor(m, 2));
    m = fminf(m, __shfl_xor(m, 4));
    if (oct == 0) {
      const float f = sym_flag[b];
      const float d2 = 2.0f * (m + sh[prow].w);
      cv[prow] = f * sqrtf(fmaxf(d2, 1e-12f)) + (1.f - f) * asy[prow];
    }
  }
  __syncthreads();

  // ---- block total: 32 leaders -> wave-0 butterfly -> one atomicAdd
  if (t < 64) {
    float v = (t < SLAB) ? cv[t] : 0.f;
#pragma unroll
    for (int off = 32; off > 0; off >>= 1) v += __shfl_xor(v, off);
    if (t == 0) atomicAdd(out, v * invNB);
  }
}

extern "C" void kernel_launch(void* const* d_in, const int* in_sizes, int n_in,
                              void* d_out, int out_size, void* d_ws, size_t ws_size,
                              hipStream_t stream) {
  const float* pred = (const float*)d_in[0];
  const float* targ = (const float*)d_in[1];
  const float* sym_flag = (const float*)d_in[2];
  float* out = (float*)d_out;

  const int B = in_sizes[2];            // 16
  const int N = in_sizes[0] / (B * 3);  // 2048

  const int slabsPerBatch = N / SLAB;   // 64

  hipMemsetAsync(out, 0, sizeof(float), stream);  // accumulator

  chamfer_onepass_kernel<<<B * slabsPerBatch, TPB, 0, stream>>>(
      pred, targ, sym_flag, out, N, B, slabsPerBatch,
      1.0f / (float)(N * B));
}

// Round 8
// 15.944 us; speedup vs baseline: 1.8033x; 1.8033x over previous
//
#include <hip/hip_runtime.h>
#include <hip/hip_bf16.h>
#include <math.h>

// MFMA chamfer: S[target r][pred c] = 0.5*t^2 - p.t computed by ONE
// v_mfma_f32_32x32x16_bf16 per 32x32 tile, with hi/lo bf16 splitting packed
// into K (11 of 16 slots used):
//   A row r (target): k0-2=th, k3-5=th, k6-7=tl.xy | k8=tl.z, k9=qh, k10=ql
//   B col c (pred)  : k0-2=-ph, k3-5=-pl, k6-7=-ph.xy | k8=-ph.z, k9=1, k10=1
// dot = -th.ph - th.pl - tl.ph + q  =  0.5*t^2 - p.t + O(1e-4).
// d^2/2 = S + 0.5*p^2 (pred-only, added after the min in kernel 2).
// C/D layout (m74/m101): col=lane&31 (pred), rows in regs + lane>>5 half.
// Min over targets = elementwise running min3 (8 regs) + in-lane tree +
// shfl_xor(32). Block = (batch, pred-panel 256, target-quarter 512):
// grid 512, 4 waves; each wave: 2 pred tiles, 16 A-iterations.

typedef short short8 __attribute__((ext_vector_type(8)));
typedef float f32x16 __attribute__((ext_vector_type(16)));

__device__ __forceinline__ unsigned short f2bf(float f) {  // RNE f32->bf16
  unsigned u = __float_as_uint(f);
  u = u + 0x7FFFu + ((u >> 16) & 1u);
  return (unsigned short)(u >> 16);
}
__device__ __forceinline__ float bf2f(unsigned short h) {
  return __uint_as_float(((unsigned)h) << 16);
}

#define K1_TPB 256
#define TQS 512    // targets per quarter (N/4)
#define PPANEL 256 // preds per block (N/8)

__global__ __launch_bounds__(K1_TPB) void chamfer_mfma_kernel(
    const float* __restrict__ pred, const float* __restrict__ targ,
    float* __restrict__ minS, float* __restrict__ out, int N, int B) {
  __shared__ short8 sA[2][TQS];  // [variant(lane-half)][target]

  const int blk = blockIdx.x;
  const int tq = blk & 3;         // target quarter
  const int pp = (blk >> 2) & 7;  // pred panel
  const int b = blk >> 5;         // batch

  if (blk == 0 && threadIdx.x == 0) out[0] = 0.f;  // for kernel2 atomics

  // ---- stage + convert this quarter's 512 targets into packed A fragments
  const float* tb = targ + ((size_t)b * N + tq * TQS) * 3;
  for (int t = threadIdx.x; t < TQS; t += K1_TPB) {
    const float x = tb[t * 3], y = tb[t * 3 + 1], z = tb[t * 3 + 2];
    const unsigned short thx = f2bf(x), thy = f2bf(y), thz = f2bf(z);
    const unsigned short tlx = f2bf(x - bf2f(thx));
    const unsigned short tly = f2bf(y - bf2f(thy));
    const unsigned short tlz = f2bf(z - bf2f(thz));
    const float q = 0.5f * (x * x + y * y + z * z);
    const unsigned short qh = f2bf(q), ql = f2bf(q - bf2f(qh));
    sA[0][t] = short8{(short)thx, (short)thy, (short)thz, (short)thx,
                      (short)thy, (short)thz, (short)tlx, (short)tly};
    sA[1][t] = short8{(short)tlz, (short)qh, (short)ql, 0, 0, 0, 0, 0};
  }

  const int lane = threadIdx.x & 63;
  const int w = threadIdx.x >> 6;
  const int g = lane >> 5;   // which K-half this lane holds
  const int l31 = lane & 31;
  const int colBase = pp * PPANEL + w * 64;  // this wave's 64 pred cols

  // ---- build B fragments (2 pred tiles per wave), negated hi/lo split
  short8 bf0, bf1;
  {
#pragma unroll
    for (int pt = 0; pt < 2; ++pt) {
      const int c = colBase + pt * 32 + l31;
      const float* pq = pred + ((size_t)b * N + c) * 3;
      const float x = pq[0], y = pq[1], z = pq[2];
      const unsigned short hx = f2bf(-x), hy = f2bf(-y), hz = f2bf(-z);
      const unsigned short lx = f2bf(-x - bf2f(hx));
      const unsigned short ly = f2bf(-y - bf2f(hy));
      const unsigned short lz = f2bf(-z - bf2f(hz));
      short8 r;
      if (g == 0)
        r = short8{(short)hx, (short)hy, (short)hz, (short)lx,
                   (short)ly, (short)lz, (short)hx, (short)hy};
      else
        r = short8{(short)hz, (short)0x3F80, (short)0x3F80, 0, 0, 0, 0, 0};
      if (pt == 0) bf0 = r; else bf1 = r;
    }
  }
  __syncthreads();

  const f32x16 zc = {0.f, 0.f, 0.f, 0.f, 0.f, 0.f, 0.f, 0.f,
                     0.f, 0.f, 0.f, 0.f, 0.f, 0.f, 0.f, 0.f};
  float rm0[8], rm1[8];
#pragma unroll
  for (int i = 0; i < 8; ++i) { rm0[i] = 3.4e38f; rm1[i] = 3.4e38f; }

  // ---- main loop: 16 target tiles; per tile: 1 ds_read_b128 + 2 MFMA + min3
#pragma unroll 4
  for (int ta = 0; ta < TQS / 32; ++ta) {
    const short8 a = sA[g][ta * 32 + l31];
    const f32x16 d0 = __builtin_amdgcn_mfma_f32_32x32x16_bf16(a, bf0, zc, 0, 0, 0);
    const f32x16 d1 = __builtin_amdgcn_mfma_f32_32x32x16_bf16(a, bf1, zc, 0, 0, 0);
#pragma unroll
    for (int i = 0; i < 8; ++i) {
      rm0[i] = fminf(rm0[i], fminf(d0[2 * i], d0[2 * i + 1]));  // v_min3
      rm1[i] = fminf(rm1[i], fminf(d1[2 * i], d1[2 * i + 1]));
    }
  }

  // ---- per-col min over this quarter's 512 targets
  float m0 = rm0[0], m1 = rm1[0];
#pragma unroll
  for (int i = 1; i < 8; ++i) { m0 = fminf(m0, rm0[i]); m1 = fminf(m1, rm1[i]); }
  m0 = fminf(m0, __shfl_xor(m0, 32));  // other row-half lives in lane^32
  m1 = fminf(m1, __shfl_xor(m1, 32));

  if (lane < 32) {
    float* dst = minS + ((size_t)(b * 4 + tq)) * N;
    dst[colBase + lane] = m0;
    dst[colBase + 32 + lane] = m1;
  }
}

// Kernel 2: per pred point, merge 4 quarter-mins, add 0.5*p^2, sqrt; asym
// term; blend; block-reduce; one atomicAdd per block (out zeroed by k1).
__global__ __launch_bounds__(256) void chamfer_final_kernel(
    const float* __restrict__ pred, const float* __restrict__ targ,
    const float* __restrict__ minS, const float* __restrict__ sym_flag,
    float* __restrict__ out, int N, int B, float invNB) {
  const int blk = blockIdx.x;
  const int b = blk >> 3;  // 8 blocks per batch
  const int i = (blk & 7) * 256 + threadIdx.x;
  const size_t col = (size_t)b * N + i;

  float m = minS[(size_t)(b * 4 + 0) * N + i];
  m = fminf(m, minS[(size_t)(b * 4 + 1) * N + i]);
  m = fminf(m, minS[(size_t)(b * 4 + 2) * N + i]);
  m = fminf(m, minS[(size_t)(b * 4 + 3) * N + i]);

  const float px = pred[col * 3], py = pred[col * 3 + 1], pz = pred[col * 3 + 2];
  const float tx = targ[col * 3], ty = targ[col * 3 + 1], tz = targ[col * 3 + 2];
  const float hp2 = 0.5f * (px * px + py * py + pz * pz);
  const float dsym = sqrtf(fmaxf(2.f * (m + hp2), 1e-12f));
  const float dx = px - tx, dy = py - ty, dz = pz - tz;
  const float dasym = sqrtf(dx * dx + dy * dy + dz * dz);
  const float f = sym_flag[b];

  float c = (f * dsym + (1.f - f) * dasym) * invNB;
#pragma unroll
  for (int off = 32; off > 0; off >>= 1) c += __shfl_xor(c, off);
  __shared__ float sW[4];
  if ((threadIdx.x & 63) == 0) sW[threadIdx.x >> 6] = c;
  __syncthreads();
  if (threadIdx.x == 0) atomicAdd(out, sW[0] + sW[1] + sW[2] + sW[3]);
}

extern "C" void kernel_launch(void* const* d_in, const int* in_sizes, int n_in,
                              void* d_out, int out_size, void* d_ws, size_t ws_size,
                              hipStream_t stream) {
  const float* pred = (const float*)d_in[0];
  const float* targ = (const float*)d_in[1];
  const float* sym_flag = (const float*)d_in[2];
  float* out = (float*)d_out;

  const int B = in_sizes[2];            // 16
  const int N = in_sizes[0] / (B * 3);  // 2048 (kernel assumes this)

  float* minS = (float*)d_ws;  // [B][4][N] f32 = 512 KB

  const int grid1 = B * 4 * (N / PPANEL);  // 16*4*8 = 512
  chamfer_mfma_kernel<<<grid1, K1_TPB, 0, stream>>>(pred, targ, minS, out, N, B);

  const int grid2 = B * (N / 256);  // 128
  chamfer_final_kernel<<<grid2, 256, 0, stream>>>(
      pred, targ, minS, sym_flag, out, N, B, 1.0f / (float)(N * B));
}